// Round 6
// baseline (252.457 us; speedup 1.0000x reference)
//
#include <hip/hip_runtime.h>
#include <stdint.h>

#define D_DIM 4096
#define N_ROWS 8192
#define ROW_STRIDE 1040        // 1024 B slab-row + 16 B skew: banks 4c%32 -> 2-way (free)
#define SLAB_BYTES (16 * ROW_STRIDE)   // 16.25 KB per wave-buffer

typedef __attribute__((ext_vector_type(8))) short bfrag8;
typedef __attribute__((ext_vector_type(4))) float facc4;
typedef unsigned long long u64;

__device__ __forceinline__ uint32_t pack_bf16x2(float lo, float hi) {
    union { float f; uint32_t u; } a, b;
    a.f = lo; b.f = hi;
    return (b.u & 0xFFFF0000u) | (a.u >> 16);   // truncate-to-bf16
}

// ---------------------------------------------------------------------------
// Kernel 0: frag-ordered bf16 B-image from A (verified since round 3).
// Granule fb = chunk*16 + t*2 + ks; slot = fb*64 + lane (16 B):
//   A[16t + (lane&15)][chunk*64 + ks*32 + (lane>>4)*8 + j], j=0..7
// ---------------------------------------------------------------------------
__global__ void __launch_bounds__(256)
prep_A(const float* __restrict__ A, uint32_t* __restrict__ Bimg) {
    const int S = blockIdx.x * 256 + threadIdx.x;  // 0..65535
    const int chunk = S >> 10;
    const int rest  = S & 1023;
    const int tks   = rest >> 6;
    const int lane  = rest & 63;
    const int t  = tks >> 1;
    const int ks = tks & 1;
    const int c  = lane & 15;
    const int q  = lane >> 4;
    const float* src = A + (size_t)(16 * t + c) * D_DIM + chunk * 64 + ks * 32 + q * 8;
    float4 f0 = *(const float4*)(src);
    float4 f1 = *(const float4*)(src + 4);
    uint4 o;
    o.x = pack_bf16x2(f0.x, f0.y);
    o.y = pack_bf16x2(f0.z, f0.w);
    o.z = pack_bf16x2(f1.x, f1.y);
    o.w = pack_bf16x2(f1.z, f1.w);
    *(uint4*)(Bimg + (size_t)S * 4) = o;
}

// ---------------------------------------------------------------------------
// Kernel 1: fused GEMM + sign-pack. Block = 16 rows x 128 cols x K=4096.
// 4 waves = 4 K-splits (1024 floats each). Wave-private LDS staging:
// slab = 256 floats x 16 rows, staged by 16 x 1KB global_load_lds (no dest
// VGPR -> 16 KB in flight per wave), double-buffered, paced by manual
// s_waitcnt vmcnt(16). NO barriers in the K-loop -> no vmcnt(0) drains.
// ---------------------------------------------------------------------------
__global__ void __launch_bounds__(256)
gemm_fused(const float* __restrict__ L, const uint32_t* __restrict__ Bimg,
           u64* __restrict__ folded) {
    __shared__ char sm[8 * SLAB_BYTES];   // 4 waves x 2 buffers = 133,120 B
    const int tid = threadIdx.x, w = tid >> 6, lane = tid & 63;
    const int row0 = blockIdx.x * 16;
    const int c = lane & 15, q = lane >> 4;
    const int k0 = w * 1024;              // wave's K-split origin (floats)

    char* buf0 = sm + (2 * w + 0) * SLAB_BYTES;
    char* buf1 = sm + (2 * w + 1) * SLAB_BYTES;
    const float* lbase = L + (size_t)row0 * D_DIM + k0;

    // stage slab sl (16 rows x 256 fp32) into buffer b: 16 fire-and-forget 1KB DMAs
#define STAGE(sl, dstbuf)                                                        \
    {                                                                            \
        const float* _s = lbase + (sl) * 256;                                    \
        _Pragma("unroll")                                                        \
        for (int _r = 0; _r < 16; _r++)                                          \
            __builtin_amdgcn_global_load_lds(                                    \
                (const __attribute__((address_space(1))) uint32_t*)              \
                    (_s + (size_t)_r * D_DIM + lane * 4),                        \
                (__attribute__((address_space(3))) uint32_t*)                    \
                    ((dstbuf) + _r * ROW_STRIDE),                                \
                16, 0, 0);                                                       \
    }

    facc4 acc[8];
#pragma unroll
    for (int t = 0; t < 8; t++) acc[t] = (facc4){0.f, 0.f, 0.f, 0.f};

    STAGE(0, buf0);
#pragma unroll
    for (int sl = 0; sl < 4; sl++) {
        if (sl == 0) STAGE(1, buf1);
        if (sl == 1) STAGE(2, buf0);
        if (sl == 2) STAGE(3, buf1);
        // chunk-k data ready when only the newest 16 DMAs may be outstanding
        if (sl < 3) __builtin_amdgcn_s_waitcnt(0x4F70);   // vmcnt(16) exp/lgkm no-wait
        else        __builtin_amdgcn_s_waitcnt(0x0F70);   // vmcnt(0)
        const char* buf = (sl & 1) ? buf1 : buf0;
#pragma unroll
        for (int ch = 0; ch < 4; ch++) {
            const int chunk = (w * 4 + sl) * 4 + ch;      // global 64-float chunk id
#pragma unroll
            for (int ks = 0; ks < 2; ks++) {
                // A-frag: lane holds L[row0 + c][k = chunk*64 + ks*32 + q*8 + j]
                const char* ap = buf + c * ROW_STRIDE + ch * 256 + ks * 128 + q * 32;
                float4 f0 = *(const float4*)(ap);
                float4 f1 = *(const float4*)(ap + 16);
                uint4 u;
                u.x = pack_bf16x2(f0.x, f0.y);
                u.y = pack_bf16x2(f0.z, f0.w);
                u.z = pack_bf16x2(f1.x, f1.y);
                u.w = pack_bf16x2(f1.z, f1.w);
                bfrag8 a = *(bfrag8*)&u;
                const uint32_t* bb = Bimg + ((size_t)(chunk * 16 + ks) * 64 + lane) * 4;
#pragma unroll
                for (int t = 0; t < 8; t++) {
                    bfrag8 b = *(const bfrag8*)(bb + (size_t)t * 512);
                    acc[t] = __builtin_amdgcn_mfma_f32_16x16x32_bf16(a, b, acc[t], 0, 0, 0);
                }
            }
        }
    }
#undef STAGE

    // ---- cross-wave K-split reduction through LDS (staging area reused) ----
    __syncthreads();
    float* red = (float*)sm;              // 3 planes x 2048 floats = 24 KB
    if (w) {
        float* dst = red + (w - 1) * 2048;
#pragma unroll
        for (int t = 0; t < 8; t++)
#pragma unroll
            for (int r = 0; r < 4; r++)
                dst[(4 * q + r) * 128 + 16 * t + c] = acc[t][r];
    }
    __syncthreads();
    if (w == 0) {
        // C/D layout (m89/m91-verified): row = 4q + r, col = 16t + c
        u64 masks[8][4];
#pragma unroll
        for (int t = 0; t < 8; t++)
#pragma unroll
            for (int r = 0; r < 4; r++) {
                const int e = (4 * q + r) * 128 + 16 * t + c;
                float v = acc[t][r] + red[e] + red[2048 + e] + red[4096 + e];
                masks[t][r] = __ballot(v > 0.0f);
            }
        if (lane < 16) {
            // output row m = lane = 4*qq + rr; mask bit for (row 4qq+rr, col 16t+cc)
            // sits at ballot-lane 16qq + cc
            const int qq = lane >> 2, rr = lane & 3;
            u64 h0 = 0, h1 = 0;
#pragma unroll
            for (int t = 0; t < 4; t++)
                h0 |= (u64)((masks[t][rr] >> (16 * qq)) & 0xFFFFull) << (16 * t);
#pragma unroll
            for (int t = 4; t < 8; t++)
                h1 |= (u64)((masks[t][rr] >> (16 * qq)) & 0xFFFFull) << (16 * (t - 4));
            folded[row0 + lane] = h0 ^ h1;   // 128 -> 64-bit key fold
        }
    }
}

// ---------------------------------------------------------------------------
// Kernel 2: ordered duplicate count, LDS-staged keys (verified since round 2).
// ---------------------------------------------------------------------------
__global__ void __launch_bounds__(256)
count_rows(const u64* __restrict__ folded, float* __restrict__ out) {
    __shared__ u64 K[N_ROWS];
    const int tid = threadIdx.x;
    for (int i = tid; i < N_ROWS / 2; i += 256)
        ((uint4*)K)[i] = ((const uint4*)folded)[i];
    __syncthreads();

    const int g    = blockIdx.x * 4 + (tid >> 6);
    const int lane = tid & 63;
    int rows[4];
    u64 my[4];
    int cnt[4] = {0, 0, 0, 0};
#pragma unroll
    for (int r = 0; r < 4; r++) {
        rows[r] = g + 2048 * r;
        my[r] = K[rows[r]];
    }
    const int maxrow = rows[3];
    for (int j = lane; j <= maxrow; j += 64) {
        u64 k = K[j];
#pragma unroll
        for (int r = 0; r < 4; r++)
            cnt[r] += (int)((j <= rows[r]) & (k == my[r]));
    }
#pragma unroll
    for (int r = 0; r < 4; r++) {
        int v = cnt[r];
#pragma unroll
        for (int o = 32; o; o >>= 1) v += __shfl_xor(v, o, 64);
        if (lane == 0) out[rows[r]] = rsqrtf((float)v);
    }
}

extern "C" void kernel_launch(void* const* d_in, const int* in_sizes, int n_in,
                              void* d_out, int out_size, void* d_ws, size_t ws_size,
                              hipStream_t stream) {
    const float* latent = (const float*)d_in[0];   // [128,64,4096] fp32
    const float* A      = (const float*)d_in[1];   // [128,4096] fp32
    float* out          = (float*)d_out;           // [8192] fp32

    // ws: Bimg 1 MB | folded 64 KB
    uint32_t* Bimg = (uint32_t*)d_ws;
    u64* folded    = (u64*)((char*)d_ws + (1 << 20));

    prep_A<<<256, 256, 0, stream>>>(A, Bimg);
    gemm_fused<<<512, 256, 0, stream>>>(latent, Bimg, folded);
    count_rows<<<512, 256, 0, stream>>>(folded, out);
}